// Round 1
// baseline (603.021 us; speedup 1.0000x reference)
//
#include <hip/hip_runtime.h>
#include <hip/hip_bf16.h>

using short8 = __attribute__((ext_vector_type(8))) short;
using f32x4  = __attribute__((ext_vector_type(4))) float;

#define B_  4
#define KD  128      // head dim / model dim k
#define T_  2048
#define H_  8
#define HK  (H_*KD)  // 1024

__device__ __forceinline__ ushort f2bf(float f) {
    // round-to-nearest-even bf16 (finite inputs)
    unsigned u = __builtin_bit_cast(unsigned, f);
    u += 0x7fffu + ((u >> 16) & 1u);
    return (ushort)(u >> 16);
}

// x: [B][KD][T_] f32  ->  xt: [B][T_][KD] bf16   (write-coalesced)
__global__ __launch_bounds__(256) void cvt_x_kernel(const float* __restrict__ x,
                                                    ushort* __restrict__ xt) {
    int idx = blockIdx.x * 256 + threadIdx.x;          // over B*T*K = 1,048,576
    int k = idx & (KD - 1);
    int t = (idx >> 7) & (T_ - 1);
    int b = idx >> 18;
    xt[idx] = f2bf(x[((long)b * KD + k) * T_ + t]);
}

__global__ __launch_bounds__(256) void cvt_w_kernel(const float* __restrict__ w,
                                                    ushort* __restrict__ o, int n) {
    int i = blockIdx.x * 256 + threadIdx.x;
    if (i < n) o[i] = f2bf(w[i]);
}

// C[m][n] = scale * sum_k A[m][k] * B[n][k];  A:[M][Kd] bf16, B:[N][Kd] bf16,
// C bf16 row-major [M][N]. Per-batch element strides sA/sB/sC (0 = shared).
__global__ __launch_bounds__(256) void gemm_abT(const ushort* __restrict__ A, long sA,
                                                const ushort* __restrict__ B, long sB,
                                                ushort* __restrict__ C, long sC,
                                                int M, int N, int Kd, float scale) {
    int b = blockIdx.z;
    A += (long)b * sA;  B += (long)b * sB;  C += (long)b * sC;
    int lane = threadIdx.x & 63;
    int w    = threadIdx.x >> 6;
    int lr = lane & 15, lg = lane >> 4;
    int m0 = blockIdx.x * 64 + (w >> 1) * 32;
    int n0 = blockIdx.y * 64 + (w & 1) * 32;

    f32x4 acc[2][2] = {};
    for (int k0 = 0; k0 < Kd; k0 += 32) {
        short8 af[2], bf[2];
        #pragma unroll
        for (int i = 0; i < 2; i++)
            af[i] = *(const short8*)(A + (long)(m0 + i*16 + lr) * Kd + k0 + lg*8);
        #pragma unroll
        for (int j = 0; j < 2; j++)
            bf[j] = *(const short8*)(B + (long)(n0 + j*16 + lr) * Kd + k0 + lg*8);
        #pragma unroll
        for (int i = 0; i < 2; i++)
            #pragma unroll
            for (int j = 0; j < 2; j++)
                acc[i][j] = __builtin_amdgcn_mfma_f32_16x16x32_bf16(af[i], bf[j], acc[i][j], 0, 0, 0);
    }
    // D: col = lane&15, row = (lane>>4)*4 + r   [verified layout]
    #pragma unroll
    for (int i = 0; i < 2; i++)
        #pragma unroll
        for (int j = 0; j < 2; j++)
            #pragma unroll
            for (int r = 0; r < 4; r++) {
                int m = m0 + i*16 + lg*4 + r;
                int n = n0 + j*16 + lr;
                C[(long)m * N + n] = f2bf(acc[i][j][r] * scale);
            }
}

// out[m][n] = sum_k A[m][k]*B[n][k] + bias[m];  f32 out, coalesced over n.
__global__ __launch_bounds__(256) void gemm_abT_f32bias(const ushort* __restrict__ A,
                                                        const ushort* __restrict__ B, long sB,
                                                        const float* __restrict__ bias,
                                                        float* __restrict__ C, long sC,
                                                        int M, int N, int Kd) {
    int b = blockIdx.z;
    B += (long)b * sB;  C += (long)b * sC;
    int lane = threadIdx.x & 63;
    int w    = threadIdx.x >> 6;
    int lr = lane & 15, lg = lane >> 4;
    int m0 = blockIdx.x * 64 + (w >> 1) * 32;
    int n0 = blockIdx.y * 64 + (w & 1) * 32;

    f32x4 acc[2][2] = {};
    for (int k0 = 0; k0 < Kd; k0 += 32) {
        short8 af[2], bf[2];
        #pragma unroll
        for (int i = 0; i < 2; i++)
            af[i] = *(const short8*)(A + (long)(m0 + i*16 + lr) * Kd + k0 + lg*8);
        #pragma unroll
        for (int j = 0; j < 2; j++)
            bf[j] = *(const short8*)(B + (long)(n0 + j*16 + lr) * Kd + k0 + lg*8);
        #pragma unroll
        for (int i = 0; i < 2; i++)
            #pragma unroll
            for (int j = 0; j < 2; j++)
                acc[i][j] = __builtin_amdgcn_mfma_f32_16x16x32_bf16(af[i], bf[j], acc[i][j], 0, 0, 0);
    }
    #pragma unroll
    for (int i = 0; i < 2; i++)
        #pragma unroll
        for (int j = 0; j < 2; j++)
            #pragma unroll
            for (int r = 0; r < 4; r++) {
                int m = m0 + i*16 + lg*4 + r;
                int n = n0 + j*16 + lr;
                C[(long)m * N + n] = acc[i][j][r] + bias[m];
            }
}

// Flash attention. qt/kt: [B][T_][HK] bf16 (q pre-scaled by 1/sqrt(KD)),
// vs: [B][HK][T_] bf16, ot: [B][T_][HK] bf16.
// Block = 4 waves; wave handles 16 queries; KVBLK = 64.
__global__ __launch_bounds__(256) void attn_kernel(const ushort* __restrict__ qt,
                                                   const ushort* __restrict__ kt,
                                                   const ushort* __restrict__ vs,
                                                   ushort* __restrict__ ot) {
    int b = blockIdx.z, h = blockIdx.y;
    int w    = threadIdx.x >> 6;
    int lane = threadIdx.x & 63;
    int lr = lane & 15, lg = lane >> 4;
    int q0 = blockIdx.x * 64 + w * 16;

    __shared__ __align__(16) ushort plds_all[4][16][72];   // pad 64->72 vs bank conflicts
    ushort (*plds)[72] = plds_all[w];

    const ushort* qbase = qt + ((long)b * T_ + q0) * HK + h * KD;
    const ushort* kbase = kt + (long)b * T_ * HK + h * KD;
    const ushort* vbase = vs + ((long)b * HK + h * KD) * T_;

    // Q fragments: A[m=q][k=d]; lane: row lr, k = dt*32 + lg*8 .. +8
    short8 a_q[4];
    #pragma unroll
    for (int dt = 0; dt < 4; dt++)
        a_q[dt] = *(const short8*)(qbase + (long)lr * HK + dt*32 + lg*8);

    f32x4 o_acc[8] = {};
    float m_r[4], l_r[4];
    #pragma unroll
    for (int r = 0; r < 4; r++) { m_r[r] = -1e30f; l_r[r] = 0.f; }

    for (int kb = 0; kb < T_; kb += 64) {
        // S = Q K^T for 4 key sub-tiles of 16
        f32x4 s[4] = {};
        #pragma unroll
        for (int nt = 0; nt < 4; nt++) {
            const ushort* kp = kbase + (long)(kb + nt*16 + lr) * HK;
            #pragma unroll
            for (int dt = 0; dt < 4; dt++) {
                short8 bf = *(const short8*)(kp + dt*32 + lg*8);
                s[nt] = __builtin_amdgcn_mfma_f32_16x16x32_bf16(a_q[dt], bf, s[nt], 0, 0, 0);
            }
        }
        // online softmax; lane holds rows lg*4+r at col lr (per 16-tile)
        float p[4][4];
        #pragma unroll
        for (int r = 0; r < 4; r++) {
            float mx = fmaxf(fmaxf(s[0][r], s[1][r]), fmaxf(s[2][r], s[3][r]));
            #pragma unroll
            for (int d = 1; d < 16; d <<= 1)
                mx = fmaxf(mx, __shfl_xor(mx, d));
            float mnew = fmaxf(m_r[r], mx);
            float corr = __expf(m_r[r] - mnew);
            m_r[r] = mnew;
            l_r[r] *= corr;
            #pragma unroll
            for (int nd = 0; nd < 8; nd++) o_acc[nd][r] *= corr;
            float lsum = 0.f;
            #pragma unroll
            for (int nt = 0; nt < 4; nt++) {
                float pv = __expf(s[nt][r] - mnew);
                p[nt][r] = pv;
                lsum += pv;
            }
            #pragma unroll
            for (int d = 1; d < 16; d <<= 1)
                lsum += __shfl_xor(lsum, d);
            l_r[r] += lsum;
        }
        // P -> LDS (bf16), [16 q rows][64 key cols]
        #pragma unroll
        for (int nt = 0; nt < 4; nt++)
            #pragma unroll
            for (int r = 0; r < 4; r++)
                plds[lg*4 + r][nt*16 + lr] = f2bf(p[nt][r]);
        __builtin_amdgcn_wave_barrier();   // pin DS write->read order (in-order LDS pipe)
        // P A-fragments: row lr, k = ks*32 + lg*8
        short8 a_p[2];
        #pragma unroll
        for (int ks = 0; ks < 2; ks++)
            a_p[ks] = *(const short8*)(&plds[lr][ks*32 + lg*8]);
        // O += P V : B[k=key][n=d] from vs rows (contiguous in t)
        #pragma unroll
        for (int nd = 0; nd < 8; nd++) {
            const ushort* vp = vbase + (long)(nd*16 + lr) * T_ + kb;
            #pragma unroll
            for (int ks = 0; ks < 2; ks++) {
                short8 bv = *(const short8*)(vp + ks*32 + lg*8);
                o_acc[nd] = __builtin_amdgcn_mfma_f32_16x16x32_bf16(a_p[ks], bv, o_acc[nd], 0, 0, 0);
            }
        }
    }
    // epilogue: O /= l, store bf16 to ot[b][q][h*128+d]
    ushort* obase = ot + ((long)b * T_ + q0) * HK + h * KD;
    #pragma unroll
    for (int r = 0; r < 4; r++) {
        float inv = 1.f / l_r[r];
        #pragma unroll
        for (int nd = 0; nd < 8; nd++)
            obase[(long)(lg*4 + r) * HK + nd*16 + lr] = f2bf(o_acc[nd][r] * inv);
    }
}

extern "C" void kernel_launch(void* const* d_in, const int* in_sizes, int n_in,
                              void* d_out, int out_size, void* d_ws, size_t ws_size,
                              hipStream_t stream) {
    const float* x  = (const float*)d_in[0];
    const float* Wq = (const float*)d_in[1];
    const float* Wk = (const float*)d_in[2];
    const float* Wv = (const float*)d_in[3];
    const float* Wu = (const float*)d_in[4];
    const float* bu = (const float*)d_in[5];
    float* out = (float*)d_out;

    // workspace carve-up (bytes)
    const size_t XT  = (size_t)B_ * T_ * KD * 2;   // 2 MB
    const size_t WB  = (size_t)HK * KD * 2;        // 256 KB each
    const size_t BIG = (size_t)B_ * T_ * HK * 2;   // 16 MB each
    size_t need = XT + 4*WB + 4*BIG;
    if (ws_size < need) return;

    char* p = (char*)d_ws;
    ushort* xt  = (ushort*)p;            p += XT;
    ushort* wqb = (ushort*)p;            p += WB;
    ushort* wkb = (ushort*)p;            p += WB;
    ushort* wvb = (ushort*)p;            p += WB;
    ushort* wub = (ushort*)p;            p += WB;
    ushort* qtb = (ushort*)p;            p += BIG;
    ushort* ktb = (ushort*)p;            p += BIG;
    ushort* vsb = (ushort*)p;            p += BIG;
    ushort* otb = (ushort*)p;            p += BIG;

    cvt_x_kernel<<<(B_*T_*KD)/256, 256, 0, stream>>>(x, xt);
    cvt_w_kernel<<<(HK*KD + 255)/256, 256, 0, stream>>>(Wq, wqb, HK*KD);
    cvt_w_kernel<<<(HK*KD + 255)/256, 256, 0, stream>>>(Wk, wkb, HK*KD);
    cvt_w_kernel<<<(HK*KD + 255)/256, 256, 0, stream>>>(Wv, wvb, HK*KD);
    cvt_w_kernel<<<(KD*HK + 255)/256, 256, 0, stream>>>(Wu, wub, KD*HK);

    const float qscale = 0.08838834764831845f;     // 1/sqrt(128)
    // qt[b][t][j] = sum_k xt[b][t][k] * Wq[j][k] * qscale
    gemm_abT<<<dim3(T_/64, HK/64, B_), 256, 0, stream>>>(
        xt, (long)T_*KD, wqb, 0, qtb, (long)T_*HK, T_, HK, KD, qscale);
    gemm_abT<<<dim3(T_/64, HK/64, B_), 256, 0, stream>>>(
        xt, (long)T_*KD, wkb, 0, ktb, (long)T_*HK, T_, HK, KD, 1.f);
    // vs[b][j][t] = sum_k Wv[j][k] * xt[b][t][k]
    gemm_abT<<<dim3(HK/64, T_/64, B_), 256, 0, stream>>>(
        wvb, 0, xt, (long)T_*KD, vsb, (long)HK*T_, HK, T_, KD, 1.f);

    attn_kernel<<<dim3(T_/64, H_, B_), 256, 0, stream>>>(qtb, ktb, vsb, otb);

    // out[b][kk][t] = sum_he Wu[kk][he] * ot[b][t][he] + bu[kk]
    gemm_abT_f32bias<<<dim3(KD/64, T_/64, B_), 256, 0, stream>>>(
        wub, otb, (long)T_*HK, bu, out, (long)KD*T_, KD, T_, HK);
}

// Round 3
// 333.835 us; speedup vs baseline: 1.8063x; 1.8063x over previous
//
#include <hip/hip_runtime.h>
#include <hip/hip_bf16.h>

using short8 = __attribute__((ext_vector_type(8))) short;
using f32x4  = __attribute__((ext_vector_type(4))) float;
using f32x16 = __attribute__((ext_vector_type(16))) float;
using uint2v = __attribute__((ext_vector_type(2))) unsigned;

#define B_  4
#define KD  128      // head dim / model dim k
#define T_  2048
#define H_  8
#define HK  (H_*KD)  // 1024

__device__ __forceinline__ ushort f2bf(float f) {
    unsigned u = __builtin_bit_cast(unsigned, f);
    u += 0x7fffu + ((u >> 16) & 1u);
    return (ushort)(u >> 16);
}

__device__ __forceinline__ unsigned cvt_pk_bf16(float lo, float hi) {
    unsigned r;
    asm("v_cvt_pk_bf16_f32 %0, %1, %2" : "=v"(r) : "v"(lo), "v"(hi));
    return r;
}

// x: [B][KD][T_] f32  ->  xt: [B][T_][KD] bf16
__global__ __launch_bounds__(256) void cvt_x_kernel(const float* __restrict__ x,
                                                    ushort* __restrict__ xt) {
    int idx = blockIdx.x * 256 + threadIdx.x;
    int k = idx & (KD - 1);
    int t = (idx >> 7) & (T_ - 1);
    int b = idx >> 18;
    xt[idx] = f2bf(x[((long)b * KD + k) * T_ + t]);
}

__global__ __launch_bounds__(256) void cvt_w_kernel(const float* __restrict__ w,
                                                    ushort* __restrict__ o, int n) {
    int i = blockIdx.x * 256 + threadIdx.x;
    if (i < n) o[i] = f2bf(w[i]);
}

// C[m][n] = scale * sum_k A[m][k] * B[n][k]; bf16 in/out
__global__ __launch_bounds__(256) void gemm_abT(const ushort* __restrict__ A, long sA,
                                                const ushort* __restrict__ B, long sB,
                                                ushort* __restrict__ C, long sC,
                                                int M, int N, int Kd, float scale) {
    int b = blockIdx.z;
    A += (long)b * sA;  B += (long)b * sB;  C += (long)b * sC;
    int lane = threadIdx.x & 63;
    int w    = threadIdx.x >> 6;
    int lr = lane & 15, lg = lane >> 4;
    int m0 = blockIdx.x * 64 + (w >> 1) * 32;
    int n0 = blockIdx.y * 64 + (w & 1) * 32;

    f32x4 acc[2][2] = {};
    for (int k0 = 0; k0 < Kd; k0 += 32) {
        short8 af[2], bf[2];
        #pragma unroll
        for (int i = 0; i < 2; i++)
            af[i] = *(const short8*)(A + (long)(m0 + i*16 + lr) * Kd + k0 + lg*8);
        #pragma unroll
        for (int j = 0; j < 2; j++)
            bf[j] = *(const short8*)(B + (long)(n0 + j*16 + lr) * Kd + k0 + lg*8);
        #pragma unroll
        for (int i = 0; i < 2; i++)
            #pragma unroll
            for (int j = 0; j < 2; j++)
                acc[i][j] = __builtin_amdgcn_mfma_f32_16x16x32_bf16(af[i], bf[j], acc[i][j], 0, 0, 0);
    }
    #pragma unroll
    for (int i = 0; i < 2; i++)
        #pragma unroll
        for (int j = 0; j < 2; j++)
            #pragma unroll
            for (int r = 0; r < 4; r++) {
                int m = m0 + i*16 + lg*4 + r;
                int n = n0 + j*16 + lr;
                C[(long)m * N + n] = f2bf(acc[i][j][r] * scale);
            }
}

// out[m][n] = sum_k A[m][k]*B[n][k] + bias[m];  f32 out
__global__ __launch_bounds__(256) void gemm_abT_f32bias(const ushort* __restrict__ A,
                                                        const ushort* __restrict__ B, long sB,
                                                        const float* __restrict__ bias,
                                                        float* __restrict__ C, long sC,
                                                        int M, int N, int Kd) {
    int b = blockIdx.z;
    B += (long)b * sB;  C += (long)b * sC;
    int lane = threadIdx.x & 63;
    int w    = threadIdx.x >> 6;
    int lr = lane & 15, lg = lane >> 4;
    int m0 = blockIdx.x * 64 + (w >> 1) * 32;
    int n0 = blockIdx.y * 64 + (w & 1) * 32;

    f32x4 acc[2][2] = {};
    for (int k0 = 0; k0 < Kd; k0 += 32) {
        short8 af[2], bf[2];
        #pragma unroll
        for (int i = 0; i < 2; i++)
            af[i] = *(const short8*)(A + (long)(m0 + i*16 + lr) * Kd + k0 + lg*8);
        #pragma unroll
        for (int j = 0; j < 2; j++)
            bf[j] = *(const short8*)(B + (long)(n0 + j*16 + lr) * Kd + k0 + lg*8);
        #pragma unroll
        for (int i = 0; i < 2; i++)
            #pragma unroll
            for (int j = 0; j < 2; j++)
                acc[i][j] = __builtin_amdgcn_mfma_f32_16x16x32_bf16(af[i], bf[j], acc[i][j], 0, 0, 0);
    }
    #pragma unroll
    for (int i = 0; i < 2; i++)
        #pragma unroll
        for (int j = 0; j < 2; j++)
            #pragma unroll
            for (int r = 0; r < 4; r++) {
                int m = m0 + i*16 + lg*4 + r;
                int n = n0 + j*16 + lr;
                C[(long)m * N + n] = acc[i][j][r] + bias[m];
            }
}

// Flash attention, 8 waves x 32 queries, 32x32x16 MFMA, swapped QK^T,
// in-register softmax (no LDS). qt pre-scaled by 1/sqrt(KD).
// qt/kt: [B][T_][HK] bf16, vs: [B][HK][T_] bf16, ot: [B][T_][HK] bf16.
__global__ __launch_bounds__(512, 2) void attn32_kernel(const ushort* __restrict__ qt,
                                                        const ushort* __restrict__ kt,
                                                        const ushort* __restrict__ vs,
                                                        ushort* __restrict__ ot) {
    // XCD-bijective decode: 256 blocks, xcd = f&7 constant per (h,b) group of 8 q-tiles
    int f = blockIdx.x;
    int xcd = f & 7, u = f >> 3;
    int qt8 = u & 7, gh = u >> 3;
    int g = xcd + 8 * gh;                  // 0..31 == h + 8*b
    int h = g & 7, b = g >> 3;
    int w    = threadIdx.x >> 6;
    int lane = threadIdx.x & 63;
    int lq = lane & 31, hi = lane >> 5;
    int hi8 = hi * 8;
    int q0w = qt8 * 256 + w * 32;

    const ushort* qbase = qt + ((size_t)b * T_ + q0w + lq) * HK + h * KD + hi8;
    const ushort* kbase = kt + (size_t)b * T_ * HK + h * KD + hi8;
    const ushort* vbase = vs + ((size_t)b * HK + h * KD) * T_;

    // Q B-fragments: col=q=lq, k(d) = dc*16 + hi*8 + e
    short8 qf[8];
    #pragma unroll
    for (int dc = 0; dc < 8; dc++)
        qf[dc] = *(const short8*)(qbase + dc * 16);

    f32x16 o_acc[4] = {};   // D[q][d]: col d = dn*32+lq, row q = crow(r,hi)
    float m_q = -1e30f, l_q = 0.f;

    for (int kb = 0; kb < T_; kb += 64) {
        // S^T = K Q^T : per lane col=q=lq, rows=keys crow(r,hi) (+32 for s1)
        f32x16 s0 = {}, s1 = {};
        const ushort* kp0 = kbase + (size_t)(kb + lq) * HK;
        const ushort* kp1 = kbase + (size_t)(kb + 32 + lq) * HK;
        #pragma unroll
        for (int dc = 0; dc < 8; dc++) {
            short8 kf0 = *(const short8*)(kp0 + dc * 16);
            short8 kf1 = *(const short8*)(kp1 + dc * 16);
            s0 = __builtin_amdgcn_mfma_f32_32x32x16_bf16(kf0, qf[dc], s0, 0, 0, 0);
            s1 = __builtin_amdgcn_mfma_f32_32x32x16_bf16(kf1, qf[dc], s1, 0, 0, 0);
        }

        // per-q max over 64 keys: in-register tree + partner-lane combine
        float mx[8];
        #pragma unroll
        for (int i = 0; i < 8; i++)
            mx[i] = fmaxf(fmaxf(s0[i], s0[i+8]), fmaxf(s1[i], s1[i+8]));
        #pragma unroll
        for (int st = 4; st > 0; st >>= 1)
            #pragma unroll
            for (int i = 0; i < st; i++) mx[i] = fmaxf(mx[i], mx[i+st]);
        float pmax = fmaxf(mx[0], __shfl_xor(mx[0], 32));

        // defer-max (T13): rescale only when max grew past threshold
        if (!__all(pmax - m_q <= 8.f)) {
            float mnew = fmaxf(m_q, pmax);
            float corr = __expf(m_q - mnew);
            l_q *= corr;
            m_q = mnew;
            #pragma unroll
            for (int r = 0; r < 16; r++) {
                float cr = __shfl(corr, (r & 3) + 8 * (r >> 2) + 4 * hi);
                #pragma unroll
                for (int dn = 0; dn < 4; dn++) o_acc[dn][r] *= cr;
            }
        }

        // P = exp(S - m), row-sum into l
        float ls0 = 0.f, ls1 = 0.f, ls2 = 0.f, ls3 = 0.f;
        #pragma unroll
        for (int r = 0; r < 16; r++) {
            float e0 = __expf(s0[r] - m_q);
            float e1 = __expf(s1[r] - m_q);
            s0[r] = e0; s1[r] = e1;
            if (r & 1) { ls1 += e0; ls3 += e1; } else { ls0 += e0; ls2 += e1; }
        }
        float lsum = (ls0 + ls1) + (ls2 + ls3);
        lsum += __shfl_xor(lsum, 32);
        l_q += lsum;

        // pack P to bf16 (16 cvt_pk) + redistribute (8 permlane32_swap).
        // permlane32_swap(vdst,vsrc): vdst.lanes[32:63] <-> vsrc.lanes[0:31]
        // (guide T12 verified call order: (lo_pair, hi_pair); both outputs used)
        unsigned uu[2][4][2];
        #pragma unroll
        for (int m4 = 0; m4 < 4; m4++) {
            uu[0][m4][0] = cvt_pk_bf16(s0[4*m4+0], s0[4*m4+1]);
            uu[0][m4][1] = cvt_pk_bf16(s0[4*m4+2], s0[4*m4+3]);
            uu[1][m4][0] = cvt_pk_bf16(s1[4*m4+0], s1[4*m4+1]);
            uu[1][m4][1] = cvt_pk_bf16(s1[4*m4+2], s1[4*m4+3]);
        }
        short8 ap[4];
        #pragma unroll
        for (int ks = 0; ks < 4; ks++) {
            int nt = ks >> 1, j = ks & 1;
            unsigned lo0 = uu[nt][2*j][0],   lo1 = uu[nt][2*j][1];
            unsigned hi0 = uu[nt][2*j+1][0], hi1 = uu[nt][2*j+1][1];
            uint2v r0 = __builtin_amdgcn_permlane32_swap(lo0, hi0, false, false);
            uint2v r1 = __builtin_amdgcn_permlane32_swap(lo1, hi1, false, false);
            union { unsigned wd[4]; short8 v; } c;
            c.wd[0] = r0[0];   // [lo_lo | hi_lo] : keys hi*8 + {0,1}
            c.wd[1] = r1[0];   // keys hi*8 + {2,3}
            c.wd[2] = r0[1];   // [lo_hi | hi_hi] : keys hi*8 + {4,5}
            c.wd[3] = r1[1];   // keys hi*8 + {6,7}
            ap[ks] = c.v;
        }

        // O += P V
        #pragma unroll
        for (int dn = 0; dn < 4; dn++) {
            const ushort* vp = vbase + (size_t)(dn*32 + lq) * T_ + kb + hi8;
            #pragma unroll
            for (int ks = 0; ks < 4; ks++) {
                short8 vf = *(const short8*)(vp + ks * 16);
                o_acc[dn] = __builtin_amdgcn_mfma_f32_32x32x16_bf16(ap[ks], vf, o_acc[dn], 0, 0, 0);
            }
        }
    }

    // epilogue: O /= l, store bf16
    float linv = 1.f / l_q;
    ushort* ob = ot + ((size_t)b * T_ + q0w) * HK + h * KD;
    #pragma unroll
    for (int r = 0; r < 16; r++) {
        int qrow = (r & 3) + 8 * (r >> 2) + 4 * hi;
        float lr_ = __shfl(linv, qrow);
        #pragma unroll
        for (int dn = 0; dn < 4; dn++)
            ob[(size_t)qrow * HK + dn*32 + lq] = f2bf(o_acc[dn][r] * lr_);
    }
}

extern "C" void kernel_launch(void* const* d_in, const int* in_sizes, int n_in,
                              void* d_out, int out_size, void* d_ws, size_t ws_size,
                              hipStream_t stream) {
    const float* x  = (const float*)d_in[0];
    const float* Wq = (const float*)d_in[1];
    const float* Wk = (const float*)d_in[2];
    const float* Wv = (const float*)d_in[3];
    const float* Wu = (const float*)d_in[4];
    const float* bu = (const float*)d_in[5];
    float* out = (float*)d_out;

    const size_t XT  = (size_t)B_ * T_ * KD * 2;
    const size_t WB  = (size_t)HK * KD * 2;
    const size_t BIG = (size_t)B_ * T_ * HK * 2;
    size_t need = XT + 4*WB + 4*BIG;
    if (ws_size < need) return;

    char* p = (char*)d_ws;
    ushort* xt  = (ushort*)p;            p += XT;
    ushort* wqb = (ushort*)p;            p += WB;
    ushort* wkb = (ushort*)p;            p += WB;
    ushort* wvb = (ushort*)p;            p += WB;
    ushort* wub = (ushort*)p;            p += WB;
    ushort* qtb = (ushort*)p;            p += BIG;
    ushort* ktb = (ushort*)p;            p += BIG;
    ushort* vsb = (ushort*)p;            p += BIG;
    ushort* otb = (ushort*)p;            p += BIG;

    cvt_x_kernel<<<(B_*T_*KD)/256, 256, 0, stream>>>(x, xt);
    cvt_w_kernel<<<(HK*KD + 255)/256, 256, 0, stream>>>(Wq, wqb, HK*KD);
    cvt_w_kernel<<<(HK*KD + 255)/256, 256, 0, stream>>>(Wk, wkb, HK*KD);
    cvt_w_kernel<<<(HK*KD + 255)/256, 256, 0, stream>>>(Wv, wvb, HK*KD);
    cvt_w_kernel<<<(KD*HK + 255)/256, 256, 0, stream>>>(Wu, wub, KD*HK);

    const float qscale = 0.08838834764831845f;     // 1/sqrt(128)
    gemm_abT<<<dim3(T_/64, HK/64, B_), 256, 0, stream>>>(
        xt, (long)T_*KD, wqb, 0, qtb, (long)T_*HK, T_, HK, KD, qscale);
    gemm_abT<<<dim3(T_/64, HK/64, B_), 256, 0, stream>>>(
        xt, (long)T_*KD, wkb, 0, ktb, (long)T_*HK, T_, HK, KD, 1.f);
    gemm_abT<<<dim3(HK/64, T_/64, B_), 256, 0, stream>>>(
        wvb, 0, xt, (long)T_*KD, vsb, (long)HK*T_, HK, T_, KD, 1.f);

    attn32_kernel<<<dim3(256), 512, 0, stream>>>(qtb, ktb, vsb, otb);

    gemm_abT_f32bias<<<dim3(KD/64, T_/64, B_), 256, 0, stream>>>(
        wub, otb, (long)T_*HK, bu, out, (long)KD*T_, KD, T_, HK);
}

// Round 4
// 165.266 us; speedup vs baseline: 3.6488x; 2.0200x over previous
//
#include <hip/hip_runtime.h>
#include <hip/hip_bf16.h>

using short8 = __attribute__((ext_vector_type(8))) short;
using f32x4  = __attribute__((ext_vector_type(4))) float;
using f32x16 = __attribute__((ext_vector_type(16))) float;
using uint2v = __attribute__((ext_vector_type(2))) unsigned;

#define B_  4
#define KD  128      // head dim / model dim k
#define T_  2048
#define H_  8
#define HK  (H_*KD)  // 1024
#define NT  (T_/64)  // 32 KV tiles

__device__ __forceinline__ ushort f2bf(float f) {
    unsigned u = __builtin_bit_cast(unsigned, f);
    u += 0x7fffu + ((u >> 16) & 1u);
    return (ushort)(u >> 16);
}

__device__ __forceinline__ unsigned cvt_pk_bf16(float lo, float hi) {
    unsigned r;
    asm("v_cvt_pk_bf16_f32 %0, %1, %2" : "=v"(r) : "v"(lo), "v"(hi));
    return r;
}

// x: [B][KD][T_] f32  ->  xt: [B][T_][KD] bf16
__global__ __launch_bounds__(256) void cvt_x_kernel(const float* __restrict__ x,
                                                    ushort* __restrict__ xt) {
    int idx = blockIdx.x * 256 + threadIdx.x;
    int k = idx & (KD - 1);
    int t = (idx >> 7) & (T_ - 1);
    int b = idx >> 18;
    xt[idx] = f2bf(x[((long)b * KD + k) * T_ + t]);
}

__global__ __launch_bounds__(256) void cvt_w_kernel(const float* __restrict__ w,
                                                    ushort* __restrict__ o, int n) {
    int i = blockIdx.x * 256 + threadIdx.x;
    if (i < n) o[i] = f2bf(w[i]);
}

// C[m][n] = scale * sum_k A[m][k] * B[n][k]; bf16 in/out
__global__ __launch_bounds__(256) void gemm_abT(const ushort* __restrict__ A, long sA,
                                                const ushort* __restrict__ B, long sB,
                                                ushort* __restrict__ C, long sC,
                                                int M, int N, int Kd, float scale) {
    int b = blockIdx.z;
    A += (long)b * sA;  B += (long)b * sB;  C += (long)b * sC;
    int lane = threadIdx.x & 63;
    int w    = threadIdx.x >> 6;
    int lr = lane & 15, lg = lane >> 4;
    int m0 = blockIdx.x * 64 + (w >> 1) * 32;
    int n0 = blockIdx.y * 64 + (w & 1) * 32;

    f32x4 acc[2][2] = {};
    for (int k0 = 0; k0 < Kd; k0 += 32) {
        short8 af[2], bf[2];
        #pragma unroll
        for (int i = 0; i < 2; i++)
            af[i] = *(const short8*)(A + (long)(m0 + i*16 + lr) * Kd + k0 + lg*8);
        #pragma unroll
        for (int j = 0; j < 2; j++)
            bf[j] = *(const short8*)(B + (long)(n0 + j*16 + lr) * Kd + k0 + lg*8);
        #pragma unroll
        for (int i = 0; i < 2; i++)
            #pragma unroll
            for (int j = 0; j < 2; j++)
                acc[i][j] = __builtin_amdgcn_mfma_f32_16x16x32_bf16(af[i], bf[j], acc[i][j], 0, 0, 0);
    }
    #pragma unroll
    for (int i = 0; i < 2; i++)
        #pragma unroll
        for (int j = 0; j < 2; j++)
            #pragma unroll
            for (int r = 0; r < 4; r++) {
                int m = m0 + i*16 + lg*4 + r;
                int n = n0 + j*16 + lr;
                C[(long)m * N + n] = f2bf(acc[i][j][r] * scale);
            }
}

// out[m][n] = sum_k A[m][k]*B[n][k] + bias[m];  f32 out
__global__ __launch_bounds__(256) void gemm_abT_f32bias(const ushort* __restrict__ A,
                                                        const ushort* __restrict__ B, long sB,
                                                        const float* __restrict__ bias,
                                                        float* __restrict__ C, long sC,
                                                        int M, int N, int Kd) {
    int b = blockIdx.z;
    B += (long)b * sB;  C += (long)b * sC;
    int lane = threadIdx.x & 63;
    int w    = threadIdx.x >> 6;
    int lr = lane & 15, lg = lane >> 4;
    int m0 = blockIdx.x * 64 + (w >> 1) * 32;
    int n0 = blockIdx.y * 64 + (w & 1) * 32;

    f32x4 acc[2][2] = {};
    for (int k0 = 0; k0 < Kd; k0 += 32) {
        short8 af[2], bf[2];
        #pragma unroll
        for (int i = 0; i < 2; i++)
            af[i] = *(const short8*)(A + (long)(m0 + i*16 + lr) * Kd + k0 + lg*8);
        #pragma unroll
        for (int j = 0; j < 2; j++)
            bf[j] = *(const short8*)(B + (long)(n0 + j*16 + lr) * Kd + k0 + lg*8);
        #pragma unroll
        for (int i = 0; i < 2; i++)
            #pragma unroll
            for (int j = 0; j < 2; j++)
                acc[i][j] = __builtin_amdgcn_mfma_f32_16x16x32_bf16(af[i], bf[j], acc[i][j], 0, 0, 0);
    }
    #pragma unroll
    for (int i = 0; i < 2; i++)
        #pragma unroll
        for (int j = 0; j < 2; j++)
            #pragma unroll
            for (int r = 0; r < 4; r++) {
                int m = m0 + i*16 + lg*4 + r;
                int n = n0 + j*16 + lr;
                C[(long)m * N + n] = acc[i][j][r] + bias[m];
            }
}

// Flash attention, 8 waves x 32 queries, 32x32x16 MFMA, swapped QK^T,
// in-register softmax. K/V tiles double-buffered in LDS (XOR-swizzled),
// reg-staged with async issue (T14). qt pre-scaled by 1/sqrt(KD).
// qt/kt: [B][T_][HK] bf16, vs: [B][HK][T_] bf16, ot: [B][T_][HK] bf16.
__global__ __launch_bounds__(512, 2) void attn32_kernel(const ushort* __restrict__ qt,
                                                        const ushort* __restrict__ kt,
                                                        const ushort* __restrict__ vs,
                                                        ushort* __restrict__ ot) {
    // XCD-bijective decode: per XCD one head, all 4 batches
    int f = blockIdx.x;
    int xcd = f & 7, u = f >> 3;
    int qt8 = u & 7, gh = u >> 3;
    int g = xcd + 8 * gh;                  // 0..31 == h + 8*b
    int h = g & 7, b = g >> 3;
    int w    = threadIdx.x >> 6;
    int lane = threadIdx.x & 63;
    int lq = lane & 31, hi = lane >> 5;
    int hi8 = hi * 8;
    int q0w = qt8 * 256 + w * 32;

    // LDS: K tiles [64 key][128 d], V tiles [128 d][64 key], both x2 buffers,
    // elem-index XOR swizzle: col ^= (row&7)<<3
    __shared__ __align__(16) ushort k_lds[2][64 * 128];
    __shared__ __align__(16) ushort v_lds[2][128 * 64];

    // staging thread constants (512 threads: K 32B/thread, V 32B/thread)
    int tid  = threadIdx.x;
    int krow = tid >> 3, kcol = (tid & 7) << 4;
    const ushort* kst = kt + ((size_t)b * T_ + krow) * HK + h * KD + kcol;
    int kwi = krow * 128 + (kcol ^ ((krow & 7) << 3));
    int vrow = tid >> 2, vcol = (tid & 3) << 4;
    const ushort* vst = vs + ((size_t)b * HK + h * KD + vrow) * T_ + vcol;
    int vwi = vrow * 64 + (vcol ^ ((vrow & 7) << 3));

    const ushort* qbase = qt + ((size_t)b * T_ + q0w + lq) * HK + h * KD + hi8;

    // Q B-fragments: col=q=lq, k(d) = dc*16 + hi*8 + e
    short8 qf[8];
    #pragma unroll
    for (int dc = 0; dc < 8; dc++)
        qf[dc] = *(const short8*)(qbase + dc * 16);

    // prologue: stage tile 0, issue loads for tile 1
    short8 rk0 = *(const short8*)(kst);
    short8 rk1 = *(const short8*)(kst + 8);
    short8 rv0 = *(const short8*)(vst);
    short8 rv1 = *(const short8*)(vst + 8);
    *(short8*)&k_lds[0][kwi]     = rk0;
    *(short8*)&k_lds[0][kwi ^ 8] = rk1;
    *(short8*)&v_lds[0][vwi]     = rv0;
    *(short8*)&v_lds[0][vwi ^ 8] = rv1;
    rk0 = *(const short8*)(kst + (size_t)64 * HK);
    rk1 = *(const short8*)(kst + (size_t)64 * HK + 8);
    rv0 = *(const short8*)(vst + 64);
    rv1 = *(const short8*)(vst + 64 + 8);
    __syncthreads();

    f32x16 o_acc[4] = {};   // D[q][d]: col d = dn*32+lq, row q = crow(r,hi)
    float m_q = -1e30f, l_q = 0.f;
    const int xsw = (lq & 7) << 3;   // read swizzle (same for all our row sets)

    for (int t = 0; t < NT; ++t) {
        const int cur = t & 1;
        // ---- QK^T from k_lds[cur] ----
        f32x16 s0 = {}, s1 = {};
        const ushort* kr0 = &k_lds[cur][(size_t)lq * 128];
        const ushort* kr1 = &k_lds[cur][(size_t)(32 + lq) * 128];
        #pragma unroll
        for (int dc = 0; dc < 8; dc++) {
            int c = (dc * 16 + hi8) ^ xsw;
            short8 kf0 = *(const short8*)(kr0 + c);
            short8 kf1 = *(const short8*)(kr1 + c);
            s0 = __builtin_amdgcn_mfma_f32_32x32x16_bf16(kf0, qf[dc], s0, 0, 0, 0);
            s1 = __builtin_amdgcn_mfma_f32_32x32x16_bf16(kf1, qf[dc], s1, 0, 0, 0);
        }

        // per-q max over 64 keys
        float mx[8];
        #pragma unroll
        for (int i = 0; i < 8; i++)
            mx[i] = fmaxf(fmaxf(s0[i], s0[i+8]), fmaxf(s1[i], s1[i+8]));
        #pragma unroll
        for (int st = 4; st > 0; st >>= 1)
            #pragma unroll
            for (int i = 0; i < st; i++) mx[i] = fmaxf(mx[i], mx[i+st]);
        float pmax = fmaxf(mx[0], __shfl_xor(mx[0], 32));

        // defer-max (T13)
        if (!__all(pmax - m_q <= 8.f)) {
            float mnew = fmaxf(m_q, pmax);
            float corr = __expf(m_q - mnew);
            l_q *= corr;
            m_q = mnew;
            #pragma unroll
            for (int r = 0; r < 16; r++) {
                float cr = __shfl(corr, (r & 3) + 8 * (r >> 2) + 4 * hi);
                #pragma unroll
                for (int dn = 0; dn < 4; dn++) o_acc[dn][r] *= cr;
            }
        }

        // P = exp(S - m), row-sum into l
        float ls0 = 0.f, ls1 = 0.f, ls2 = 0.f, ls3 = 0.f;
        #pragma unroll
        for (int r = 0; r < 16; r++) {
            float e0 = __expf(s0[r] - m_q);
            float e1 = __expf(s1[r] - m_q);
            s0[r] = e0; s1[r] = e1;
            if (r & 1) { ls1 += e0; ls3 += e1; } else { ls0 += e0; ls2 += e1; }
        }
        float lsum = (ls0 + ls1) + (ls2 + ls3);
        lsum += __shfl_xor(lsum, 32);
        l_q += lsum;

        // pack P to bf16 + permlane redistribute (T12, verified r3)
        unsigned uu[2][4][2];
        #pragma unroll
        for (int m4 = 0; m4 < 4; m4++) {
            uu[0][m4][0] = cvt_pk_bf16(s0[4*m4+0], s0[4*m4+1]);
            uu[0][m4][1] = cvt_pk_bf16(s0[4*m4+2], s0[4*m4+3]);
            uu[1][m4][0] = cvt_pk_bf16(s1[4*m4+0], s1[4*m4+1]);
            uu[1][m4][1] = cvt_pk_bf16(s1[4*m4+2], s1[4*m4+3]);
        }
        short8 ap[4];
        #pragma unroll
        for (int ks = 0; ks < 4; ks++) {
            int nt = ks >> 1, j = ks & 1;
            unsigned lo0 = uu[nt][2*j][0],   lo1 = uu[nt][2*j][1];
            unsigned hi0 = uu[nt][2*j+1][0], hi1 = uu[nt][2*j+1][1];
            uint2v r0 = __builtin_amdgcn_permlane32_swap(lo0, hi0, false, false);
            uint2v r1 = __builtin_amdgcn_permlane32_swap(lo1, hi1, false, false);
            union { unsigned wd[4]; short8 v; } c;
            c.wd[0] = r0[0];
            c.wd[1] = r1[0];
            c.wd[2] = r0[1];
            c.wd[3] = r1[1];
            ap[ks] = c.v;
        }

        // ---- O += P V from v_lds[cur] ----
        #pragma unroll
        for (int dn = 0; dn < 4; dn++) {
            const ushort* vr = &v_lds[cur][(size_t)(dn*32 + lq) * 64];
            #pragma unroll
            for (int ks = 0; ks < 4; ks++) {
                int c = (ks * 16 + hi8) ^ xsw;
                short8 vf = *(const short8*)(vr + c);
                o_acc[dn] = __builtin_amdgcn_mfma_f32_32x32x16_bf16(ap[ks], vf, o_acc[dn], 0, 0, 0);
            }
        }

        __syncthreads();                    // all waves done reading buf[cur]
        if (t + 1 < NT) {
            const int nxt = cur ^ 1;
            *(short8*)&k_lds[nxt][kwi]     = rk0;
            *(short8*)&k_lds[nxt][kwi ^ 8] = rk1;
            *(short8*)&v_lds[nxt][vwi]     = rv0;
            *(short8*)&v_lds[nxt][vwi ^ 8] = rv1;
            if (t + 2 < NT) {
                size_t ko = (size_t)(t + 2) * 64 * HK;
                int    vo = (t + 2) * 64;
                rk0 = *(const short8*)(kst + ko);
                rk1 = *(const short8*)(kst + ko + 8);
                rv0 = *(const short8*)(vst + vo);
                rv1 = *(const short8*)(vst + vo + 8);
            }
            __syncthreads();                // staged writes visible
        }
    }

    // epilogue: O /= l, store bf16
    float linv = 1.f / l_q;
    ushort* ob = ot + ((size_t)b * T_ + q0w) * HK + h * KD;
    #pragma unroll
    for (int r = 0; r < 16; r++) {
        int qrow = (r & 3) + 8 * (r >> 2) + 4 * hi;
        float lr_ = __shfl(linv, qrow);
        #pragma unroll
        for (int dn = 0; dn < 4; dn++)
            ob[(size_t)qrow * HK + dn*32 + lq] = f2bf(o_acc[dn][r] * lr_);
    }
}

extern "C" void kernel_launch(void* const* d_in, const int* in_sizes, int n_in,
                              void* d_out, int out_size, void* d_ws, size_t ws_size,
                              hipStream_t stream) {
    const float* x  = (const float*)d_in[0];
    const float* Wq = (const float*)d_in[1];
    const float* Wk = (const float*)d_in[2];
    const float* Wv = (const float*)d_in[3];
    const float* Wu = (const float*)d_in[4];
    const float* bu = (const float*)d_in[5];
    float* out = (float*)d_out;

    const size_t XT  = (size_t)B_ * T_ * KD * 2;
    const size_t WB  = (size_t)HK * KD * 2;
    const size_t BIG = (size_t)B_ * T_ * HK * 2;
    size_t need = XT + 4*WB + 4*BIG;
    if (ws_size < need) return;

    char* p = (char*)d_ws;
    ushort* xt  = (ushort*)p;            p += XT;
    ushort* wqb = (ushort*)p;            p += WB;
    ushort* wkb = (ushort*)p;            p += WB;
    ushort* wvb = (ushort*)p;            p += WB;
    ushort* wub = (ushort*)p;            p += WB;
    ushort* qtb = (ushort*)p;            p += BIG;
    ushort* ktb = (ushort*)p;            p += BIG;
    ushort* vsb = (ushort*)p;            p += BIG;
    ushort* otb = (ushort*)p;            p += BIG;

    cvt_x_kernel<<<(B_*T_*KD)/256, 256, 0, stream>>>(x, xt);
    cvt_w_kernel<<<(HK*KD + 255)/256, 256, 0, stream>>>(Wq, wqb, HK*KD);
    cvt_w_kernel<<<(HK*KD + 255)/256, 256, 0, stream>>>(Wk, wkb, HK*KD);
    cvt_w_kernel<<<(HK*KD + 255)/256, 256, 0, stream>>>(Wv, wvb, HK*KD);
    cvt_w_kernel<<<(KD*HK + 255)/256, 256, 0, stream>>>(Wu, wub, KD*HK);

    const float qscale = 0.08838834764831845f;     // 1/sqrt(128)
    gemm_abT<<<dim3(T_/64, HK/64, B_), 256, 0, stream>>>(
        xt, (long)T_*KD, wqb, 0, qtb, (long)T_*HK, T_, HK, KD, qscale);
    gemm_abT<<<dim3(T_/64, HK/64, B_), 256, 0, stream>>>(
        xt, (long)T_*KD, wkb, 0, ktb, (long)T_*HK, T_, HK, KD, 1.f);
    gemm_abT<<<dim3(HK/64, T_/64, B_), 256, 0, stream>>>(
        wvb, 0, xt, (long)T_*KD, vsb, (long)HK*T_, HK, T_, KD, 1.f);

    attn32_kernel<<<dim3(256), 512, 0, stream>>>(qtb, ktb, vsb, otb);

    gemm_abT_f32bias<<<dim3(KD/64, T_/64, B_), 256, 0, stream>>>(
        wub, otb, (long)T_*HK, bu, out, (long)KD*T_, KD, T_, HK);
}